// Round 5
// baseline (168.031 us; speedup 1.0000x reference)
//
#include <hip/hip_runtime.h>

#define BB 32
#define SS 512
#define LL 64
#define TSTART 61
#define TSTOP 62
#define NSEG 16
#define SEGLEN 32
#define QPAD 68

typedef short short8 __attribute__((ext_vector_type(8)));
typedef float floatx4 __attribute__((ext_vector_type(4)));

union S8 { int i[4]; short8 v; };

__device__ inline unsigned bf16_rne(float x) {
    unsigned u = __float_as_uint(x);
    u += 0x7fffu + ((u >> 16) & 1u);
    return u >> 16;
}
__device__ inline int pack_bf16(float a, float b) {
    return (int)(bf16_rne(a) | (bf16_rne(b) << 16));
}

// ---------------- combine chain (device fn): fold a0 through 16 segment products ----
// One wave; two register banks, 1-segment-ahead prefetch, no spills.
__device__ void combine_batch(int b, int j, const float* __restrict__ enc,
                              const float* __restrict__ Tr, const int* __restrict__ lens,
                              const float* __restrict__ wsQ, const float* __restrict__ wsS,
                              float* __restrict__ out)
{
    const int len = lens[b];
    const float* qb = wsQ + (size_t)b * NSEG * 4096;

    float alpha0 = Tr[TSTART * LL + j] + enc[b * (SS * LL) + j];
    float m = alpha0;
    #pragma unroll
    for (int off = 32; off; off >>= 1) m = fmaxf(m, __shfl_xor(m, off));
    float a = __expf(alpha0 - m);
    float logscale = m;

    float myscale = wsS[b * (NSEG * 4) + j];   // (s,g) = (j>>2, j&3)

    float A[64], Bv[64];
    #pragma unroll
    for (int c = 0; c < 64; ++c) A[c] = qb[c * 64 + j];   // seg 0

    auto step = [&](int s, float (&cur)[64]) {
        float l0 = __shfl(myscale, 4 * s + 0);
        float l1 = __shfl(myscale, 4 * s + 1);
        float l2 = __shfl(myscale, 4 * s + 2);
        float l3 = __shfl(myscale, 4 * s + 3);
        float lmax = fmaxf(fmaxf(l0, l1), fmaxf(l2, l3));
        int grp = j >> 4;
        float lgg = (grp == 0) ? l0 : (grp == 1) ? l1 : (grp == 2) ? l2 : l3;
        float at = a * __expf(lgg - lmax);
        int ai = __float_as_int(at);
        float s0 = 0.f, s1 = 0.f, s2 = 0.f, s3 = 0.f;
        #pragma unroll
        for (int c = 0; c < 16; ++c) {
            s0 = fmaf(__int_as_float(__builtin_amdgcn_readlane(ai, 4 * c + 0)), cur[4 * c + 0], s0);
            s1 = fmaf(__int_as_float(__builtin_amdgcn_readlane(ai, 4 * c + 1)), cur[4 * c + 1], s1);
            s2 = fmaf(__int_as_float(__builtin_amdgcn_readlane(ai, 4 * c + 2)), cur[4 * c + 2], s2);
            s3 = fmaf(__int_as_float(__builtin_amdgcn_readlane(ai, 4 * c + 3)), cur[4 * c + 3], s3);
        }
        float an = ((s0 + s1) + (s2 + s3));
        float mx = an;
        #pragma unroll
        for (int off = 32; off; off >>= 1) mx = fmaxf(mx, __shfl_xor(mx, off));
        a = an * (1.0f / mx);
        logscale += lmax + __logf(mx);
    };

    for (int s = 0; s < 16; s += 2) {
        const float* q1 = qb + (size_t)min(s + 1, NSEG - 1) * 4096;
        #pragma unroll
        for (int c = 0; c < 64; ++c) Bv[c] = q1[c * 64 + j];
        step(s, A);
        const float* q2 = qb + (size_t)min(s + 2, NSEG - 1) * 4096;
        #pragma unroll
        for (int c = 0; c < 64; ++c) A[c] = q2[c * 64 + j];
        step(s + 1, Bv);
    }

    float f = a * __expf(Tr[j * LL + TSTOP]);
    float ssum = f;
    #pragma unroll
    for (int off = 32; off; off >>= 1) ssum += __shfl_xor(ssum, off);
    if (j == 0) {
        const float LN2x7 = 7.0f * 0.69314718055994530942f;
        out[b] = logscale + (float)(len - 1) * LN2x7 + __logf(ssum);
    }
}

// ---------------- fused kernel ----------------
// Blocks 0..2047 (one wave): segment product for unit = blockIdx
//   (b=unit>>6, s=(unit>>2)&15, g=unit&3); after writing P^T, last arriver of
//   the batch's 64 units (atomic counter) runs the combine chain for that batch.
// Blocks 2048..2079: labeled path for batch blockIdx-2048 (one wave).
__global__ __launch_bounds__(64) void crf_fused_kernel(
    const float* __restrict__ enc, const float* __restrict__ Tr,
    const int* __restrict__ lens, const int* __restrict__ tags,
    float* __restrict__ wsQ, float* __restrict__ wsS, int* __restrict__ cnt,
    float* __restrict__ out)
{
    const int blk = blockIdx.x;
    const int lane = threadIdx.x;

    if (blk >= BB * NSEG * 4) {
        // ---------------- labeled path (one wave) ----------------
        const int b = blk - BB * NSEG * 4;
        const int len = lens[b];
        const int* tg = tags + b * SS;
        const float* eb = enc + b * (SS * LL);
        float acc = 0.f;
        for (int t = 1 + lane; t < len; t += 64) {
            int curt = tg[t], prevt = tg[t - 1];
            acc += Tr[prevt * LL + curt] + eb[t * LL + curt];
        }
        #pragma unroll
        for (int off = 32; off; off >>= 1) acc += __shfl_xor(acc, off);
        if (lane == 0) {
            int t0 = tg[0], te = tg[len - 1];
            acc += Tr[TSTART * LL + t0] + eb[t0];
            acc += Tr[te * LL + TSTOP];
            out[BB + b] = acc;
        }
        return;
    }

    const int b = blk >> 6;
    const int s = (blk >> 2) & 15;
    const int g = blk & 3;
    const int len = lens[b];
    const int q = lane >> 4;
    const int lcol = lane & 15;
    const float* eb = enc + b * (SS * LL);
    const int tlo = SEGLEN * s + 1;
    const int Teff = min(max(len - tlo, 0), SEGLEN);

    float* qdst = wsQ + (size_t)(b * NSEG + s) * 4096;

    if (Teff <= 0) {   // segment past len: transfer = identity
        #pragma unroll
        for (int u = 0; u < 4; ++u) {
            int r0 = 16 * q + 4 * u;
            float4 v;
            v.x = (r0 + 0 == 16 * g + lcol) ? 1.f : 0.f;
            v.y = (r0 + 1 == 16 * g + lcol) ? 1.f : 0.f;
            v.z = (r0 + 2 == 16 * g + lcol) ? 1.f : 0.f;
            v.w = (r0 + 3 == 16 * g + lcol) ? 1.f : 0.f;
            *(float4*)(qdst + (16 * g + lcol) * 64 + r0) = v;
        }
        if (lane == 0) wsS[(b * NSEG + s) * 4 + g] = 0.f;
    } else {
        __shared__ __align__(16) float QT[16 * QPAD];
        __shared__ __align__(16) float W32[32 * 64];

        // A operand: A[m][k] = E^T[m][k] = exp(T[k][m]) * 2^-7 (bf16, RNE)
        short8 Afr[4][2];
        #pragma unroll
        for (int mt = 0; mt < 4; ++mt)
            #pragma unroll
            for (int c2 = 0; c2 < 2; ++c2) {
                float av[8];
                #pragma unroll
                for (int idx = 0; idx < 8; ++idx) {
                    int kk = 32 * c2 + 8 * q + idx;
                    int mm = 16 * mt + lcol;
                    av[idx] = __expf(Tr[kk * LL + mm]) * 0.0078125f;
                }
                S8 u;
                #pragma unroll
                for (int w2 = 0; w2 < 4; ++w2) u.i[w2] = pack_bf16(av[2 * w2], av[2 * w2 + 1]);
                Afr[mt][c2] = u.v;
            }

        // QT init: column 16g+lcol of E^T
        {
            const float* trow = Tr + (16 * g + lcol) * LL;
            #pragma unroll
            for (int u = 0; u < 4; ++u) {
                float4 tv = *(const float4*)(trow + 16 * q + 4 * u);
                float4 ev;
                ev.x = __expf(tv.x) * 0.0078125f;
                ev.y = __expf(tv.y) * 0.0078125f;
                ev.z = __expf(tv.z) * 0.0078125f;
                ev.w = __expf(tv.w) * 0.0078125f;
                *(float4*)(QT + lcol * QPAD + 16 * q + 4 * u) = ev;
            }
        }

        float lg = 0.0f;
        float ecur[8], enxt[8];
        #pragma unroll
        for (int k = 0; k < 8; ++k) ecur[k] = eb[min(tlo + k, SS - 1) * LL + lane];
        #pragma unroll
        for (int k = 0; k < 8; ++k) enxt[k] = eb[min(tlo + 8 + k, SS - 1) * LL + lane];

        for (int cc = 0; cc < 4; ++cc) {
            #pragma unroll
            for (int k = 0; k < 8; ++k) W32[(8 * cc + k) * 64 + lane] = __expf(ecur[k]);
            float epre[8];
            #pragma unroll
            for (int k = 0; k < 8; ++k) epre[k] = eb[min(tlo + 8 * (cc + 2) + k, SS - 1) * LL + lane];

            #pragma unroll
            for (int k = 0; k < 8; ++k) {
                const int i = 8 * cc + k + 2;     // step index 2..33
                if (i <= Teff) {
                    const int wloc = 8 * cc + k;
                    float4 qv[2][2], wv[2][2];
                    #pragma unroll
                    for (int c2 = 0; c2 < 2; ++c2)
                        #pragma unroll
                        for (int h = 0; h < 2; ++h) {
                            qv[c2][h] = *(const float4*)(QT + lcol * QPAD + 32 * c2 + 8 * q + 4 * h);
                            wv[c2][h] = *(const float4*)(W32 + wloc * 64 + 32 * c2 + 8 * q + 4 * h);
                        }
                    short8 Bfr[2];
                    #pragma unroll
                    for (int c2 = 0; c2 < 2; ++c2) {
                        float bv[8];
                        bv[0] = qv[c2][0].x * wv[c2][0].x;  bv[1] = qv[c2][0].y * wv[c2][0].y;
                        bv[2] = qv[c2][0].z * wv[c2][0].z;  bv[3] = qv[c2][0].w * wv[c2][0].w;
                        bv[4] = qv[c2][1].x * wv[c2][1].x;  bv[5] = qv[c2][1].y * wv[c2][1].y;
                        bv[6] = qv[c2][1].z * wv[c2][1].z;  bv[7] = qv[c2][1].w * wv[c2][1].w;
                        S8 u;
                        #pragma unroll
                        for (int w2 = 0; w2 < 4; ++w2)
                            u.i[w2] = pack_bf16(bv[2 * w2], bv[2 * w2 + 1]);
                        Bfr[c2] = u.v;
                    }
                    float ov[4][4];
                    #pragma unroll
                    for (int mt = 0; mt < 4; ++mt) {
                        floatx4 z = {0.f, 0.f, 0.f, 0.f};
                        z = __builtin_amdgcn_mfma_f32_16x16x32_bf16(Afr[mt][0], Bfr[0], z, 0, 0, 0);
                        z = __builtin_amdgcn_mfma_f32_16x16x32_bf16(Afr[mt][1], Bfr[1], z, 0, 0, 0);
                        ov[mt][0] = z[0]; ov[mt][1] = z[1]; ov[mt][2] = z[2]; ov[mt][3] = z[3];
                    }
                    if (k == 7) {
                        float mx = ov[0][0];
                        #pragma unroll
                        for (int mt = 0; mt < 4; ++mt)
                            #pragma unroll
                            for (int r = 0; r < 4; ++r) mx = fmaxf(mx, ov[mt][r]);
                        #pragma unroll
                        for (int off = 32; off; off >>= 1) mx = fmaxf(mx, __shfl_xor(mx, off));
                        lg += __logf(mx);
                        float rmx = 1.0f / mx;
                        #pragma unroll
                        for (int mt = 0; mt < 4; ++mt)
                            #pragma unroll
                            for (int r = 0; r < 4; ++r) ov[mt][r] *= rmx;
                    }
                    #pragma unroll
                    for (int mt = 0; mt < 4; ++mt) {
                        float4 sv = make_float4(ov[mt][0], ov[mt][1], ov[mt][2], ov[mt][3]);
                        *(float4*)(QT + lcol * QPAD + 16 * mt + 4 * q) = sv;
                    }
                }
            }
            #pragma unroll
            for (int k = 0; k < 8; ++k) { ecur[k] = enxt[k]; enxt[k] = epre[k]; }
        }

        // final row scale by w_last, write P^T [col][row]
        const float* wl = W32 + (Teff - 1) * 64;
        #pragma unroll
        for (int u = 0; u < 4; ++u) {
            int r0 = 16 * q + 4 * u;
            float4 mv = *(const float4*)(QT + lcol * QPAD + r0);
            float4 wv = *(const float4*)(wl + r0);
            float4 o = make_float4(mv.x * wv.x, mv.y * wv.y, mv.z * wv.z, mv.w * wv.w);
            *(float4*)(qdst + (16 * g + lcol) * 64 + r0) = o;
        }
        if (lane == 0) wsS[(b * NSEG + s) * 4 + g] = lg;
    }

    // -------- last arriver of this batch's 64 units runs the combine --------
    __threadfence();                         // release: P^T + wsS visible device-wide
    int old = 0;
    if (lane == 0) old = atomicAdd(&cnt[b], 1);
    old = __shfl(old, 0);
    if (old == 63) {
        __threadfence();                     // acquire: see all 64 units' writes
        combine_batch(b, lane, enc, Tr, lens, wsQ, wsS, out);
    }
}

// ---------------- Fallback (exact, used if ws too small) ----------------
__global__ __launch_bounds__(256) void crf_kernel_fb(
    const float* __restrict__ enc, const float* __restrict__ Tr,
    const int* __restrict__ lens, const int* __restrict__ tags,
    float* __restrict__ out)
{
    if (blockIdx.x < BB) {
        const int tid = threadIdx.x;
        if (tid >= 64) return;
        const int b = blockIdx.x;
        const int j = tid;
        const int len = lens[b];
        const float* eb = enc + b * (SS * LL);
        float Ecol[LL];
        #pragma unroll
        for (int i = 0; i < LL; ++i) Ecol[i] = __expf(Tr[i * LL + j]) * 0.0078125f;
        float alpha0 = Tr[TSTART * LL + j] + eb[j];
        float m = alpha0;
        #pragma unroll
        for (int off = 32; off; off >>= 1) m = fmaxf(m, __shfl_xor(m, off));
        float a = __expf(alpha0 - m);
        float logscale = m;
        float ecur[4], enext[4];
        #pragma unroll
        for (int k = 0; k < 4; ++k) ecur[k] = eb[k * LL + j];
        #pragma unroll
        for (int k = 0; k < 4; ++k) enext[k] = eb[(4 + k) * LL + j];
        const int nchunk = (len + 3) >> 2;
        for (int c = 0; c < nchunk; ++c) {
            const int cpre = (c + 2 < 128) ? (c + 2) : 127;
            float efar[4];
            #pragma unroll
            for (int k = 0; k < 4; ++k) efar[k] = eb[(4 * cpre + k) * LL + j];
            #pragma unroll
            for (int k = 0; k < 4; ++k) {
                const int t = 4 * c + k;
                if (t >= 1 && t < len) {
                    const float w = __expf(ecur[k]);
                    const int ai = __float_as_int(a);
                    float s0 = 0.f, s1 = 0.f, s2 = 0.f, s3 = 0.f;
                    #pragma unroll
                    for (int qq = 0; qq < 16; ++qq) {
                        s0 = fmaf(__int_as_float(__builtin_amdgcn_readlane(ai, 4 * qq + 0)), Ecol[4 * qq + 0], s0);
                        s1 = fmaf(__int_as_float(__builtin_amdgcn_readlane(ai, 4 * qq + 1)), Ecol[4 * qq + 1], s1);
                        s2 = fmaf(__int_as_float(__builtin_amdgcn_readlane(ai, 4 * qq + 2)), Ecol[4 * qq + 2], s2);
                        s3 = fmaf(__int_as_float(__builtin_amdgcn_readlane(ai, 4 * qq + 3)), Ecol[4 * qq + 3], s3);
                    }
                    a = ((s0 + s1) + (s2 + s3)) * w;
                    if ((t & 7) == 7) {
                        float mm = a;
                        #pragma unroll
                        for (int off = 32; off; off >>= 1) mm = fmaxf(mm, __shfl_xor(mm, off));
                        logscale += __logf(mm);
                        a = a * (1.0f / mm);
                    }
                }
            }
            #pragma unroll
            for (int k = 0; k < 4; ++k) { ecur[k] = enext[k]; enext[k] = efar[k]; }
        }
        float f = a * __expf(Tr[j * LL + TSTOP]);
        float ssum = f;
        #pragma unroll
        for (int off = 32; off; off >>= 1) ssum += __shfl_xor(ssum, off);
        if (j == 0) {
            const float LN2x7 = 7.0f * 0.69314718055994530942f;
            out[b] = logscale + (float)(len - 1) * LN2x7 + __logf(ssum);
        }
    } else {
        const int b = blockIdx.x - BB;
        const int tid = threadIdx.x;
        const int len = lens[b];
        const int* tg = tags + b * SS;
        const float* eb = enc + b * (SS * LL);
        float acc = 0.f;
        for (int t = 1 + tid; t < len; t += 256) {
            int curt = tg[t], prevt = tg[t - 1];
            acc += Tr[prevt * LL + curt] + eb[t * LL + curt];
        }
        #pragma unroll
        for (int off = 32; off; off >>= 1) acc += __shfl_xor(acc, off);
        __shared__ float red[4];
        if ((tid & 63) == 0) red[tid >> 6] = acc;
        __syncthreads();
        if (tid == 0) {
            float tot = (red[0] + red[1]) + (red[2] + red[3]);
            int t0 = tg[0], te = tg[len - 1];
            tot += Tr[TSTART * LL + t0] + eb[t0];
            tot += Tr[te * LL + TSTOP];
            out[BB + b] = tot;
        }
    }
}

extern "C" void kernel_launch(void* const* d_in, const int* in_sizes, int n_in,
                              void* d_out, int out_size, void* d_ws, size_t ws_size,
                              hipStream_t stream) {
    const float* enc  = (const float*)d_in[0];
    const float* Tr   = (const float*)d_in[1];
    const int*   lens = (const int*)d_in[2];
    const int*   tags = (const int*)d_in[3];
    float* out = (float*)d_out;

    const size_t needQ = (size_t)BB * NSEG * 4096 * sizeof(float);   // 8 MB
    const size_t needS = (size_t)BB * NSEG * 4 * sizeof(float);      // 8 KB
    const size_t needC = (size_t)BB * sizeof(int);
    if (ws_size >= needQ + needS + needC) {
        float* wsQ = (float*)d_ws;
        float* wsS = (float*)((char*)d_ws + needQ);
        int*   cnt = (int*)((char*)d_ws + needQ + needS);
        hipMemsetAsync(cnt, 0, needC, stream);   // ws is poisoned 0xAA each call
        crf_fused_kernel<<<BB * NSEG * 4 + BB, 64, 0, stream>>>(enc, Tr, lens, tags, wsQ, wsS, cnt, out);
    } else {
        crf_kernel_fb<<<2 * BB, 256, 0, stream>>>(enc, Tr, lens, tags, out);
    }
}

// Round 6
// 114.892 us; speedup vs baseline: 1.4625x; 1.4625x over previous
//
#include <hip/hip_runtime.h>

#define BB 32
#define SS 512
#define LL 64
#define TSTART 61
#define TSTOP 62
#define NSEG 32
#define SEGLEN 16
#define QPAD 68

typedef short short8 __attribute__((ext_vector_type(8)));
typedef float floatx4 __attribute__((ext_vector_type(4)));

union S8 { int i[4]; short8 v; };

__device__ inline unsigned bf16_rne(float x) {
    unsigned u = __float_as_uint(x);
    u += 0x7fffu + ((u >> 16) & 1u);
    return u >> 16;
}
__device__ inline int pack_bf16(float a, float b) {
    return (int)(bf16_rne(a) | (bf16_rne(b) << 16));
}

// ---------------- Kernel 1: segment transfer-matrix products ----------------
// Blocks 0..4095: one wave; unit=blk: b=blk>>7, s=(blk>>2)&31, g=blk&3.
//   P_seg = D(w_last)*prod[E^T*D(w_t)]*E^T over t in [16s+1, min(16s+17,len)),
//   cols [16g,16g+16). Chain depth = Teff-1 <= 15 MFMA steps.
//   Inactive units (seg past len) exit immediately; combine skips them.
// Blocks 4096..4127: labeled path for batch blk-4096 (one wave).
__global__ __launch_bounds__(64) void crf_seg_kernel(
    const float* __restrict__ enc, const float* __restrict__ Tr,
    const int* __restrict__ lens, const int* __restrict__ tags,
    float* __restrict__ wsQ, float* __restrict__ wsS,
    float* __restrict__ out)
{
    const int blk = blockIdx.x;
    const int lane = threadIdx.x;

    if (blk >= BB * NSEG * 4) {
        // ---------------- labeled path (one wave) ----------------
        const int b = blk - BB * NSEG * 4;
        const int len = lens[b];
        const int* tg = tags + b * SS;
        const float* eb = enc + b * (SS * LL);
        float acc = 0.f;
        for (int t = 1 + lane; t < len; t += 64) {
            int curt = tg[t], prevt = tg[t - 1];
            acc += Tr[prevt * LL + curt] + eb[t * LL + curt];
        }
        #pragma unroll
        for (int off = 32; off; off >>= 1) acc += __shfl_xor(acc, off);
        if (lane == 0) {
            int t0 = tg[0], te = tg[len - 1];
            acc += Tr[TSTART * LL + t0] + eb[t0];
            acc += Tr[te * LL + TSTOP];
            out[BB + b] = acc;
        }
        return;
    }

    const int b = blk >> 7;
    const int s = (blk >> 2) & 31;
    const int g = blk & 3;
    const int len = lens[b];
    const int tlo = SEGLEN * s + 1;
    const int Teff = min(len - tlo, SEGLEN);
    if (Teff <= 0) return;                 // combine skips s >= smax

    const int q = lane >> 4;
    const int lcol = lane & 15;
    const float* eb = enc + b * (SS * LL);
    float* qdst = wsQ + (size_t)(b * NSEG + s) * 4096;

    __shared__ __align__(16) float QT[16 * QPAD];   // running product [col][row]
    __shared__ __align__(16) float W16[16 * 64];    // staged w vectors [tt][row]

    // encoder rows for this segment (16 coalesced loads, in flight during setup)
    float ev[16];
    #pragma unroll
    for (int k = 0; k < 16; ++k) ev[k] = eb[min(tlo + k, SS - 1) * LL + lane];

    // A operand: A[m][k] = E^T[m][k] = exp(T[k][m]) * 2^-7 (bf16 RNE)
    short8 Afr[4][2];
    #pragma unroll
    for (int mt = 0; mt < 4; ++mt)
        #pragma unroll
        for (int c2 = 0; c2 < 2; ++c2) {
            float av[8];
            #pragma unroll
            for (int idx = 0; idx < 8; ++idx) {
                int kk = 32 * c2 + 8 * q + idx;
                int mm = 16 * mt + lcol;
                av[idx] = __expf(Tr[kk * LL + mm]) * 0.0078125f;
            }
            S8 u;
            #pragma unroll
            for (int w2 = 0; w2 < 4; ++w2) u.i[w2] = pack_bf16(av[2 * w2], av[2 * w2 + 1]);
            Afr[mt][c2] = u.v;
        }

    // QT init: column 16g+lcol of E^T
    {
        const float* trow = Tr + (16 * g + lcol) * LL;
        #pragma unroll
        for (int u = 0; u < 4; ++u) {
            float4 tv = *(const float4*)(trow + 16 * q + 4 * u);
            float4 evv;
            evv.x = __expf(tv.x) * 0.0078125f;
            evv.y = __expf(tv.y) * 0.0078125f;
            evv.z = __expf(tv.z) * 0.0078125f;
            evv.w = __expf(tv.w) * 0.0078125f;
            *(float4*)(QT + lcol * QPAD + 16 * q + 4 * u) = evv;
        }
    }

    // stage all 16 w rows up front (off the MFMA chain)
    #pragma unroll
    for (int k = 0; k < 16; ++k) W16[k * 64 + lane] = __expf(ev[k]);

    float lg = 0.0f;
    #pragma unroll
    for (int cc = 0; cc < 2; ++cc) {
        #pragma unroll
        for (int k = 0; k < 8; ++k) {
            const int i = 8 * cc + k + 2;         // step index 2..17
            if (i <= Teff) {                      // wave-uniform
                const int wloc = 8 * cc + k;      // uses w_{tlo+i-2}
                float4 qv[2][2], wv[2][2];
                #pragma unroll
                for (int c2 = 0; c2 < 2; ++c2)
                    #pragma unroll
                    for (int h = 0; h < 2; ++h) {
                        qv[c2][h] = *(const float4*)(QT + lcol * QPAD + 32 * c2 + 8 * q + 4 * h);
                        wv[c2][h] = *(const float4*)(W16 + wloc * 64 + 32 * c2 + 8 * q + 4 * h);
                    }
                short8 Bfr[2];
                #pragma unroll
                for (int c2 = 0; c2 < 2; ++c2) {
                    float bv[8];
                    bv[0] = qv[c2][0].x * wv[c2][0].x;  bv[1] = qv[c2][0].y * wv[c2][0].y;
                    bv[2] = qv[c2][0].z * wv[c2][0].z;  bv[3] = qv[c2][0].w * wv[c2][0].w;
                    bv[4] = qv[c2][1].x * wv[c2][1].x;  bv[5] = qv[c2][1].y * wv[c2][1].y;
                    bv[6] = qv[c2][1].z * wv[c2][1].z;  bv[7] = qv[c2][1].w * wv[c2][1].w;
                    S8 u;
                    #pragma unroll
                    for (int w2 = 0; w2 < 4; ++w2)
                        u.i[w2] = pack_bf16(bv[2 * w2], bv[2 * w2 + 1]);
                    Bfr[c2] = u.v;
                }
                float ov[4][4];
                #pragma unroll
                for (int mt = 0; mt < 4; ++mt) {
                    floatx4 z = {0.f, 0.f, 0.f, 0.f};
                    z = __builtin_amdgcn_mfma_f32_16x16x32_bf16(Afr[mt][0], Bfr[0], z, 0, 0, 0);
                    z = __builtin_amdgcn_mfma_f32_16x16x32_bf16(Afr[mt][1], Bfr[1], z, 0, 0, 0);
                    ov[mt][0] = z[0]; ov[mt][1] = z[1]; ov[mt][2] = z[2]; ov[mt][3] = z[3];
                }
                if (cc == 0 && k == 7) {          // single mid-chain rescale (i=9)
                    float mx = ov[0][0];
                    #pragma unroll
                    for (int mt = 0; mt < 4; ++mt)
                        #pragma unroll
                        for (int r = 0; r < 4; ++r) mx = fmaxf(mx, ov[mt][r]);
                    #pragma unroll
                    for (int off = 32; off; off >>= 1) mx = fmaxf(mx, __shfl_xor(mx, off));
                    lg += __logf(mx);
                    float rmx = 1.0f / mx;
                    #pragma unroll
                    for (int mt = 0; mt < 4; ++mt)
                        #pragma unroll
                        for (int r = 0; r < 4; ++r) ov[mt][r] *= rmx;
                }
                #pragma unroll
                for (int mt = 0; mt < 4; ++mt) {
                    float4 sv = make_float4(ov[mt][0], ov[mt][1], ov[mt][2], ov[mt][3]);
                    *(float4*)(QT + lcol * QPAD + 16 * mt + 4 * q) = sv;
                }
            }
        }
    }

    // final row scale by w_last, write P^T [col][row]
    const float* wl = W16 + (Teff - 1) * 64;
    #pragma unroll
    for (int u = 0; u < 4; ++u) {
        int r0 = 16 * q + 4 * u;
        float4 mv = *(const float4*)(QT + lcol * QPAD + r0);
        float4 wv = *(const float4*)(wl + r0);
        float4 o = make_float4(mv.x * wv.x, mv.y * wv.y, mv.z * wv.z, mv.w * wv.w);
        *(float4*)(qdst + (16 * g + lcol) * 64 + r0) = o;
    }
    if (lane == 0) wsS[(b * NSEG + s) * 4 + g] = lg;
}

// ---------------- Kernel 2: streaming fold of a0 through active segments -----
// One wave per batch. 4 rotating 16-float buffers, 3-chunk lookahead; only
// segments with tlo < len are folded (smax = (len-2)/16 + 1).
__global__ __launch_bounds__(64) void crf_combine_kernel(
    const float* __restrict__ enc, const float* __restrict__ Tr,
    const int* __restrict__ lens,
    const float* __restrict__ wsQ, const float* __restrict__ wsS,
    float* __restrict__ out)
{
    const int b = blockIdx.x;
    const int j = threadIdx.x;
    const int len = lens[b];
    const int smax = (len - 2) / SEGLEN + 1;   // active segments
    const float* qb = wsQ + (size_t)b * NSEG * 4096;

    float alpha0 = Tr[TSTART * LL + j] + enc[b * (SS * LL) + j];
    float m = alpha0;
    #pragma unroll
    for (int off = 32; off; off >>= 1) m = fmaxf(m, __shfl_xor(m, off));
    float a = __expf(alpha0 - m);
    float logscale = m;

    // per-unit log scales: 128 per batch, lanes hold two halves
    float sc0 = wsS[b * (NSEG * 4) + j];
    float sc1 = wsS[b * (NSEG * 4) + 64 + j];

    float B0[16], B1[16], B2[16], B3[16];
    auto load16 = [&](float (&Bf)[16], int chunk) {
        const float* p = qb + (size_t)chunk * 1024 + j;
        #pragma unroll
        for (int u = 0; u < 16; ++u) Bf[u] = p[u * 64];
    };
    load16(B0, 0); load16(B1, 1); load16(B2, 2);

    const int CMAX = 4 * NSEG - 1;
    for (int s = 0; s < smax; ++s) {
        // scales of this segment's 4 col-groups
        float l0, l1, l2, l3;
        if (s < 16) {
            l0 = __shfl(sc0, 4 * s + 0); l1 = __shfl(sc0, 4 * s + 1);
            l2 = __shfl(sc0, 4 * s + 2); l3 = __shfl(sc0, 4 * s + 3);
        } else {
            int e = 4 * (s - 16);
            l0 = __shfl(sc1, e + 0); l1 = __shfl(sc1, e + 1);
            l2 = __shfl(sc1, e + 2); l3 = __shfl(sc1, e + 3);
        }
        float lmax = fmaxf(fmaxf(l0, l1), fmaxf(l2, l3));
        int grp = j >> 4;
        float lgg = (grp == 0) ? l0 : (grp == 1) ? l1 : (grp == 2) ? l2 : l3;
        float at = a * __expf(lgg - lmax);
        int ai = __float_as_int(at);

        float a0 = 0.f, a1 = 0.f, a2 = 0.f, a3 = 0.f;
        const int sb = 4 * s;
        #define MAC16(BUF, BASE)                                                        \
            { _Pragma("unroll")                                                         \
              for (int u = 0; u < 16; u += 4) {                                         \
                a0 = fmaf(__int_as_float(__builtin_amdgcn_readlane(ai, BASE + u + 0)), BUF[u + 0], a0); \
                a1 = fmaf(__int_as_float(__builtin_amdgcn_readlane(ai, BASE + u + 1)), BUF[u + 1], a1); \
                a2 = fmaf(__int_as_float(__builtin_amdgcn_readlane(ai, BASE + u + 2)), BUF[u + 2], a2); \
                a3 = fmaf(__int_as_float(__builtin_amdgcn_readlane(ai, BASE + u + 3)), BUF[u + 3], a3); \
              } }
        load16(B3, min(sb + 3, CMAX));  MAC16(B0, 0);
        load16(B0, min(sb + 4, CMAX));  MAC16(B1, 16);
        load16(B1, min(sb + 5, CMAX));  MAC16(B2, 32);
        load16(B2, min(sb + 6, CMAX));  MAC16(B3, 48);
        #undef MAC16

        float an = (a0 + a1) + (a2 + a3);
        float mx = an;
        #pragma unroll
        for (int off = 32; off; off >>= 1) mx = fmaxf(mx, __shfl_xor(mx, off));
        a = an * (1.0f / mx);
        logscale += lmax + __logf(mx);
    }

    float f = a * __expf(Tr[j * LL + TSTOP]);
    float ssum = f;
    #pragma unroll
    for (int off = 32; off; off >>= 1) ssum += __shfl_xor(ssum, off);
    if (j == 0) {
        const float LN2x7 = 7.0f * 0.69314718055994530942f;
        out[b] = logscale + (float)(len - 1) * LN2x7 + __logf(ssum);
    }
}

// ---------------- Fallback (exact, used if ws too small) ----------------
__global__ __launch_bounds__(256) void crf_kernel_fb(
    const float* __restrict__ enc, const float* __restrict__ Tr,
    const int* __restrict__ lens, const int* __restrict__ tags,
    float* __restrict__ out)
{
    if (blockIdx.x < BB) {
        const int tid = threadIdx.x;
        if (tid >= 64) return;
        const int b = blockIdx.x;
        const int j = tid;
        const int len = lens[b];
        const float* eb = enc + b * (SS * LL);
        float Ecol[LL];
        #pragma unroll
        for (int i = 0; i < LL; ++i) Ecol[i] = __expf(Tr[i * LL + j]) * 0.0078125f;
        float alpha0 = Tr[TSTART * LL + j] + eb[j];
        float m = alpha0;
        #pragma unroll
        for (int off = 32; off; off >>= 1) m = fmaxf(m, __shfl_xor(m, off));
        float a = __expf(alpha0 - m);
        float logscale = m;
        float ecur[4], enext[4];
        #pragma unroll
        for (int k = 0; k < 4; ++k) ecur[k] = eb[k * LL + j];
        #pragma unroll
        for (int k = 0; k < 4; ++k) enext[k] = eb[(4 + k) * LL + j];
        const int nchunk = (len + 3) >> 2;
        for (int c = 0; c < nchunk; ++c) {
            const int cpre = (c + 2 < 128) ? (c + 2) : 127;
            float efar[4];
            #pragma unroll
            for (int k = 0; k < 4; ++k) efar[k] = eb[(4 * cpre + k) * LL + j];
            #pragma unroll
            for (int k = 0; k < 4; ++k) {
                const int t = 4 * c + k;
                if (t >= 1 && t < len) {
                    const float w = __expf(ecur[k]);
                    const int ai = __float_as_int(a);
                    float s0 = 0.f, s1 = 0.f, s2 = 0.f, s3 = 0.f;
                    #pragma unroll
                    for (int qq = 0; qq < 16; ++qq) {
                        s0 = fmaf(__int_as_float(__builtin_amdgcn_readlane(ai, 4 * qq + 0)), Ecol[4 * qq + 0], s0);
                        s1 = fmaf(__int_as_float(__builtin_amdgcn_readlane(ai, 4 * qq + 1)), Ecol[4 * qq + 1], s1);
                        s2 = fmaf(__int_as_float(__builtin_amdgcn_readlane(ai, 4 * qq + 2)), Ecol[4 * qq + 2], s2);
                        s3 = fmaf(__int_as_float(__builtin_amdgcn_readlane(ai, 4 * qq + 3)), Ecol[4 * qq + 3], s3);
                    }
                    a = ((s0 + s1) + (s2 + s3)) * w;
                    if ((t & 7) == 7) {
                        float mm = a;
                        #pragma unroll
                        for (int off = 32; off; off >>= 1) mm = fmaxf(mm, __shfl_xor(mm, off));
                        logscale += __logf(mm);
                        a = a * (1.0f / mm);
                    }
                }
            }
            #pragma unroll
            for (int k = 0; k < 4; ++k) { ecur[k] = enext[k]; enext[k] = efar[k]; }
        }
        float f = a * __expf(Tr[j * LL + TSTOP]);
        float ssum = f;
        #pragma unroll
        for (int off = 32; off; off >>= 1) ssum += __shfl_xor(ssum, off);
        if (j == 0) {
            const float LN2x7 = 7.0f * 0.69314718055994530942f;
            out[b] = logscale + (float)(len - 1) * LN2x7 + __logf(ssum);
        }
    } else {
        const int b = blockIdx.x - BB;
        const int tid = threadIdx.x;
        const int len = lens[b];
        const int* tg = tags + b * SS;
        const float* eb = enc + b * (SS * LL);
        float acc = 0.f;
        for (int t = 1 + tid; t < len; t += 256) {
            int curt = tg[t], prevt = tg[t - 1];
            acc += Tr[prevt * LL + curt] + eb[t * LL + curt];
        }
        #pragma unroll
        for (int off = 32; off; off >>= 1) acc += __shfl_xor(acc, off);
        __shared__ float red[4];
        if ((tid & 63) == 0) red[tid >> 6] = acc;
        __syncthreads();
        if (tid == 0) {
            float tot = (red[0] + red[1]) + (red[2] + red[3]);
            int t0 = tg[0], te = tg[len - 1];
            tot += Tr[TSTART * LL + t0] + eb[t0];
            tot += Tr[te * LL + TSTOP];
            out[BB + b] = tot;
        }
    }
}

extern "C" void kernel_launch(void* const* d_in, const int* in_sizes, int n_in,
                              void* d_out, int out_size, void* d_ws, size_t ws_size,
                              hipStream_t stream) {
    const float* enc  = (const float*)d_in[0];
    const float* Tr   = (const float*)d_in[1];
    const int*   lens = (const int*)d_in[2];
    const int*   tags = (const int*)d_in[3];
    float* out = (float*)d_out;

    const size_t needQ = (size_t)BB * NSEG * 4096 * sizeof(float);   // 16 MB
    const size_t needS = (size_t)BB * NSEG * 4 * sizeof(float);      // 16 KB
    if (ws_size >= needQ + needS) {
        float* wsQ = (float*)d_ws;
        float* wsS = (float*)((char*)d_ws + needQ);
        crf_seg_kernel<<<BB * NSEG * 4 + BB, 64, 0, stream>>>(enc, Tr, lens, tags, wsQ, wsS, out);
        crf_combine_kernel<<<BB, 64, 0, stream>>>(enc, Tr, lens, wsQ, wsS, out);
    } else {
        crf_kernel_fb<<<2 * BB, 256, 0, stream>>>(enc, Tr, lens, tags, out);
    }
}

// Round 7
// 100.494 us; speedup vs baseline: 1.6720x; 1.1433x over previous
//
#include <hip/hip_runtime.h>

#define BB 32
#define SS 512
#define LL 64
#define TSTART 61
#define TSTOP 62
#define NSEG 32
#define SEGLEN 16
#define QPAD 68

typedef short short8 __attribute__((ext_vector_type(8)));
typedef float floatx4 __attribute__((ext_vector_type(4)));

union S8 { int i[4]; uint4 u4; short8 v; };

// half-up bf16 round + pack (positive values only): 4 VALU ops
__device__ inline int pack_bf16(float a, float b) {
    unsigned ua = __float_as_uint(a) + 0x8000u;
    unsigned ub = __float_as_uint(b) + 0x8000u;
    return (int)((ua >> 16) | (ub & 0xffff0000u));
}

// ---------------- Kernel 1: segment transfer-matrix products ----------------
// Blocks 0..4095: one wave; unit=blk: b=blk>>7, s=(blk>>2)&31, g=blk&3.
//   P_seg = D(w_last)*prod[E^T*D(w_t)]*E^T over t in [16s+1, min(16s+17,len)),
//   cols [16g,16g+16). Output P^T stored BF16 row-major in (col,row) — exactly
//   the A-fragment layout the combine kernel needs.
// Blocks 4096..4127: labeled path for batch blk-4096 (one wave).
__global__ __launch_bounds__(64) void crf_seg_kernel(
    const float* __restrict__ enc, const float* __restrict__ Tr,
    const int* __restrict__ lens, const int* __restrict__ tags,
    unsigned short* __restrict__ wsQ, float* __restrict__ wsS,
    float* __restrict__ out)
{
    const int blk = blockIdx.x;
    const int lane = threadIdx.x;

    if (blk >= BB * NSEG * 4) {
        // ---------------- labeled path (one wave) ----------------
        const int b = blk - BB * NSEG * 4;
        const int len = lens[b];
        const int* tg = tags + b * SS;
        const float* eb = enc + b * (SS * LL);
        float acc = 0.f;
        for (int t = 1 + lane; t < len; t += 64) {
            int curt = tg[t], prevt = tg[t - 1];
            acc += Tr[prevt * LL + curt] + eb[t * LL + curt];
        }
        #pragma unroll
        for (int off = 32; off; off >>= 1) acc += __shfl_xor(acc, off);
        if (lane == 0) {
            int t0 = tg[0], te = tg[len - 1];
            acc += Tr[TSTART * LL + t0] + eb[t0];
            acc += Tr[te * LL + TSTOP];
            out[BB + b] = acc;
        }
        return;
    }

    const int b = blk >> 7;
    const int s = (blk >> 2) & 31;
    const int g = blk & 3;
    const int len = lens[b];
    const int tlo = SEGLEN * s + 1;
    const int Teff = min(len - tlo, SEGLEN);
    if (Teff <= 0) return;                 // combine skips s >= smax

    const int q = lane >> 4;
    const int lcol = lane & 15;
    const float* eb = enc + b * (SS * LL);

    __shared__ __align__(16) float QT[16 * QPAD];   // running product [col][row]
    __shared__ __align__(16) float W16[16 * 64];    // staged w vectors [tt][row]

    // encoder rows for this segment (coalesced, issued early)
    float ev[16];
    #pragma unroll
    for (int k = 0; k < 16; ++k) ev[k] = eb[min(tlo + k, SS - 1) * LL + lane];

    // A operand: A[m][k] = E^T[m][k] = exp(T[k][m]) * 2^-7 (bf16)
    short8 Afr[4][2];
    #pragma unroll
    for (int mt = 0; mt < 4; ++mt)
        #pragma unroll
        for (int c2 = 0; c2 < 2; ++c2) {
            float av[8];
            #pragma unroll
            for (int idx = 0; idx < 8; ++idx) {
                int kk = 32 * c2 + 8 * q + idx;
                int mm = 16 * mt + lcol;
                av[idx] = __expf(Tr[kk * LL + mm]) * 0.0078125f;
            }
            S8 u;
            #pragma unroll
            for (int w2 = 0; w2 < 4; ++w2) u.i[w2] = pack_bf16(av[2 * w2], av[2 * w2 + 1]);
            Afr[mt][c2] = u.v;
        }

    // QT init: column 16g+lcol of E^T
    {
        const float* trow = Tr + (16 * g + lcol) * LL;
        #pragma unroll
        for (int u = 0; u < 4; ++u) {
            float4 tv = *(const float4*)(trow + 16 * q + 4 * u);
            float4 evv;
            evv.x = __expf(tv.x) * 0.0078125f;
            evv.y = __expf(tv.y) * 0.0078125f;
            evv.z = __expf(tv.z) * 0.0078125f;
            evv.w = __expf(tv.w) * 0.0078125f;
            *(float4*)(QT + lcol * QPAD + 16 * q + 4 * u) = evv;
        }
    }

    // stage all 16 w rows up front (off the MFMA chain)
    #pragma unroll
    for (int k = 0; k < 16; ++k) W16[k * 64 + lane] = __expf(ev[k]);

    float lg = 0.0f;
    #pragma unroll
    for (int cc = 0; cc < 2; ++cc) {
        #pragma unroll
        for (int k = 0; k < 8; ++k) {
            const int i = 8 * cc + k + 2;         // step index 2..17
            if (i <= Teff) {                      // wave-uniform
                const int wloc = 8 * cc + k;      // uses w_{tlo+i-2}
                float4 qv[2][2], wv[2][2];
                #pragma unroll
                for (int c2 = 0; c2 < 2; ++c2)
                    #pragma unroll
                    for (int h = 0; h < 2; ++h) {
                        qv[c2][h] = *(const float4*)(QT + lcol * QPAD + 32 * c2 + 8 * q + 4 * h);
                        wv[c2][h] = *(const float4*)(W16 + wloc * 64 + 32 * c2 + 8 * q + 4 * h);
                    }
                short8 Bfr[2];
                #pragma unroll
                for (int c2 = 0; c2 < 2; ++c2) {
                    S8 u;
                    u.i[0] = pack_bf16(qv[c2][0].x * wv[c2][0].x, qv[c2][0].y * wv[c2][0].y);
                    u.i[1] = pack_bf16(qv[c2][0].z * wv[c2][0].z, qv[c2][0].w * wv[c2][0].w);
                    u.i[2] = pack_bf16(qv[c2][1].x * wv[c2][1].x, qv[c2][1].y * wv[c2][1].y);
                    u.i[3] = pack_bf16(qv[c2][1].z * wv[c2][1].z, qv[c2][1].w * wv[c2][1].w);
                    Bfr[c2] = u.v;
                }
                float ov[4][4];
                #pragma unroll
                for (int mt = 0; mt < 4; ++mt) {
                    floatx4 z = {0.f, 0.f, 0.f, 0.f};
                    z = __builtin_amdgcn_mfma_f32_16x16x32_bf16(Afr[mt][0], Bfr[0], z, 0, 0, 0);
                    z = __builtin_amdgcn_mfma_f32_16x16x32_bf16(Afr[mt][1], Bfr[1], z, 0, 0, 0);
                    ov[mt][0] = z[0]; ov[mt][1] = z[1]; ov[mt][2] = z[2]; ov[mt][3] = z[3];
                }
                if (cc == 0 && k == 7) {          // single mid-chain rescale (i=9)
                    float mx = ov[0][0];
                    #pragma unroll
                    for (int mt = 0; mt < 4; ++mt)
                        #pragma unroll
                        for (int r = 0; r < 4; ++r) mx = fmaxf(mx, ov[mt][r]);
                    #pragma unroll
                    for (int off = 32; off; off >>= 1) mx = fmaxf(mx, __shfl_xor(mx, off));
                    lg += __logf(mx);
                    float rmx = 1.0f / mx;
                    #pragma unroll
                    for (int mt = 0; mt < 4; ++mt)
                        #pragma unroll
                        for (int r = 0; r < 4; ++r) ov[mt][r] *= rmx;
                }
                #pragma unroll
                for (int mt = 0; mt < 4; ++mt) {
                    float4 sv = make_float4(ov[mt][0], ov[mt][1], ov[mt][2], ov[mt][3]);
                    *(float4*)(QT + lcol * QPAD + 16 * mt + 4 * q) = sv;
                }
            }
        }
    }

    // final row scale by w_last; write P^T as BF16 [col][row]
    const float* wl = W16 + (Teff - 1) * 64;
    unsigned short* qdst = wsQ + (size_t)(b * NSEG + s) * 4096 + (16 * g + lcol) * 64;
    #pragma unroll
    for (int u = 0; u < 2; ++u) {
        const int r0 = 16 * q + 8 * u;
        float4 m0 = *(const float4*)(QT + lcol * QPAD + r0);
        float4 m1 = *(const float4*)(QT + lcol * QPAD + r0 + 4);
        float4 w0 = *(const float4*)(wl + r0);
        float4 w1 = *(const float4*)(wl + r0 + 4);
        S8 o;
        o.i[0] = pack_bf16(m0.x * w0.x, m0.y * w0.y);
        o.i[1] = pack_bf16(m0.z * w0.z, m0.w * w0.w);
        o.i[2] = pack_bf16(m1.x * w1.x, m1.y * w1.y);
        o.i[3] = pack_bf16(m1.z * w1.z, m1.w * w1.w);
        *(uint4*)(qdst + r0) = o.u4;
    }
    if (lane == 0) wsS[(b * NSEG + s) * 4 + g] = lg;
}

// ---------------- Kernel 2: MFMA-based fold of a0 through active segments ----
// One wave per batch. Per fold: A = P_s^T (bf16 from ws, double-banked 2 folds
// ahead), B = a broadcast into all 16 cols (result replicated per col).
__global__ __launch_bounds__(64) void crf_combine_kernel(
    const float* __restrict__ enc, const float* __restrict__ Tr,
    const int* __restrict__ lens,
    const unsigned short* __restrict__ wsQ, const float* __restrict__ wsS,
    float* __restrict__ out)
{
    const int b = blockIdx.x;
    const int j = threadIdx.x;
    const int len = lens[b];
    const int smax = (len - 2) / SEGLEN + 1;   // active segments (len >= 256)
    const int q = j >> 4;
    const int lcol = j & 15;

    const uint4* qb = (const uint4*)(wsQ + (size_t)b * NSEG * 4096);
    // uint4 index within a fold (512 uint4/fold) for frag (mt,c2):
    int fidx[4][2];
    #pragma unroll
    for (int mt = 0; mt < 4; ++mt)
        #pragma unroll
        for (int c2 = 0; c2 < 2; ++c2)
            fidx[mt][c2] = (16 * mt + lcol) * 8 + 4 * c2 + q;

    __shared__ __align__(16) float Al[64];    // current alpha (linear, pre-normalized)

    float sc0 = wsS[b * (NSEG * 4) + j];      // per-unit log scales (4s+g -> lane)
    float sc1 = wsS[b * (NSEG * 4) + 64 + j];

    float alpha0 = Tr[TSTART * LL + j] + enc[b * (SS * LL) + j];
    float m = alpha0;
    #pragma unroll
    for (int off = 32; off; off >>= 1) m = fmaxf(m, __shfl_xor(m, off));
    Al[j] = __expf(alpha0 - m);
    float logscale = m;
    float invmx = 1.0f;

    uint4 Abuf0[8], Abuf1[8];
    {
        const uint4* p1 = qb + (size_t)min(1, smax - 1) * 512;
        #pragma unroll
        for (int mt = 0; mt < 4; ++mt)
            #pragma unroll
            for (int c2 = 0; c2 < 2; ++c2) {
                Abuf0[mt * 2 + c2] = qb[fidx[mt][c2]];
                Abuf1[mt * 2 + c2] = p1[fidx[mt][c2]];
            }
    }

    int s = 0;
    auto fold = [&](uint4 (&cur)[8]) {
        // B frags: broadcast-read a, apply pending 1/mx, pack bf16
        float4 q0 = *(const float4*)(Al + 8 * q);
        float4 q1 = *(const float4*)(Al + 8 * q + 4);
        float4 q2 = *(const float4*)(Al + 32 + 8 * q);
        float4 q3 = *(const float4*)(Al + 32 + 8 * q + 4);
        S8 b0, b1;
        b0.i[0] = pack_bf16(q0.x * invmx, q0.y * invmx);
        b0.i[1] = pack_bf16(q0.z * invmx, q0.w * invmx);
        b0.i[2] = pack_bf16(q1.x * invmx, q1.y * invmx);
        b0.i[3] = pack_bf16(q1.z * invmx, q1.w * invmx);
        b1.i[0] = pack_bf16(q2.x * invmx, q2.y * invmx);
        b1.i[1] = pack_bf16(q2.z * invmx, q2.w * invmx);
        b1.i[2] = pack_bf16(q3.x * invmx, q3.y * invmx);
        b1.i[3] = pack_bf16(q3.z * invmx, q3.w * invmx);

        S8 a8[8];
        #pragma unroll
        for (int f = 0; f < 8; ++f) a8[f].u4 = cur[f];

        // prefetch fold s+2 into the bank just consumed
        const uint4* pn = qb + (size_t)min(s + 2, smax - 1) * 512;
        #pragma unroll
        for (int mt = 0; mt < 4; ++mt)
            #pragma unroll
            for (int c2 = 0; c2 < 2; ++c2) cur[mt * 2 + c2] = pn[fidx[mt][c2]];

        floatx4 acc[4];
        #pragma unroll
        for (int mt = 0; mt < 4; ++mt) {
            floatx4 z = {0.f, 0.f, 0.f, 0.f};
            z = __builtin_amdgcn_mfma_f32_16x16x32_bf16(a8[2 * mt].v, b0.v, z, 0, 0, 0);
            z = __builtin_amdgcn_mfma_f32_16x16x32_bf16(a8[2 * mt + 1].v, b1.v, z, 0, 0, 0);
            acc[mt] = z;
        }

        // per-col-group scale compensation (output row m's group = mt)
        float l0, l1, l2, l3;
        if (s < 16) {
            l0 = __shfl(sc0, 4 * s + 0); l1 = __shfl(sc0, 4 * s + 1);
            l2 = __shfl(sc0, 4 * s + 2); l3 = __shfl(sc0, 4 * s + 3);
        } else {
            int e = 4 * (s - 16);
            l0 = __shfl(sc1, e + 0); l1 = __shfl(sc1, e + 1);
            l2 = __shfl(sc1, e + 2); l3 = __shfl(sc1, e + 3);
        }
        float lmax = fmaxf(fmaxf(l0, l1), fmaxf(l2, l3));
        float e0 = __expf(l0 - lmax), e1 = __expf(l1 - lmax);
        float e2 = __expf(l2 - lmax), e3 = __expf(l3 - lmax);
        #pragma unroll
        for (int r = 0; r < 4; ++r) {
            acc[0][r] *= e0; acc[1][r] *= e1; acc[2][r] *= e2; acc[3][r] *= e3;
        }

        // writeback rows 16mt+4q+r from the lcol==0 lanes (cols replicated)
        if (lcol == 0) {
            #pragma unroll
            for (int mt = 0; mt < 4; ++mt)
                *(float4*)(Al + 16 * mt + 4 * q) =
                    make_float4(acc[mt][0], acc[mt][1], acc[mt][2], acc[mt][3]);
        }

        // wave max: lanes differ only in q -> 2 xor steps
        float mx = acc[0][0];
        #pragma unroll
        for (int mt = 0; mt < 4; ++mt)
            #pragma unroll
            for (int r = 0; r < 4; ++r) mx = fmaxf(mx, acc[mt][r]);
        mx = fmaxf(mx, __shfl_xor(mx, 16));
        mx = fmaxf(mx, __shfl_xor(mx, 32));
        invmx = 1.0f / mx;
        logscale += lmax + __logf(mx);
    };

    while (s < smax) {
        fold(Abuf0);
        ++s;
        if (s >= smax) break;
        fold(Abuf1);
        ++s;
    }

    float aj = Al[j] * invmx;
    float f = aj * __expf(Tr[j * LL + TSTOP]);
    float ssum = f;
    #pragma unroll
    for (int off = 32; off; off >>= 1) ssum += __shfl_xor(ssum, off);
    if (j == 0) {
        const float LN2x7 = 7.0f * 0.69314718055994530942f;
        out[b] = logscale + (float)(len - 1) * LN2x7 + __logf(ssum);
    }
}

// ---------------- Fallback (exact, used if ws too small) ----------------
__global__ __launch_bounds__(256) void crf_kernel_fb(
    const float* __restrict__ enc, const float* __restrict__ Tr,
    const int* __restrict__ lens, const int* __restrict__ tags,
    float* __restrict__ out)
{
    if (blockIdx.x < BB) {
        const int tid = threadIdx.x;
        if (tid >= 64) return;
        const int b = blockIdx.x;
        const int j = tid;
        const int len = lens[b];
        const float* eb = enc + b * (SS * LL);
        float Ecol[LL];
        #pragma unroll
        for (int i = 0; i < LL; ++i) Ecol[i] = __expf(Tr[i * LL + j]) * 0.0078125f;
        float alpha0 = Tr[TSTART * LL + j] + eb[j];
        float m = alpha0;
        #pragma unroll
        for (int off = 32; off; off >>= 1) m = fmaxf(m, __shfl_xor(m, off));
        float a = __expf(alpha0 - m);
        float logscale = m;
        float ecur[4], enext[4];
        #pragma unroll
        for (int k = 0; k < 4; ++k) ecur[k] = eb[k * LL + j];
        #pragma unroll
        for (int k = 0; k < 4; ++k) enext[k] = eb[(4 + k) * LL + j];
        const int nchunk = (len + 3) >> 2;
        for (int c = 0; c < nchunk; ++c) {
            const int cpre = (c + 2 < 128) ? (c + 2) : 127;
            float efar[4];
            #pragma unroll
            for (int k = 0; k < 4; ++k) efar[k] = eb[(4 * cpre + k) * LL + j];
            #pragma unroll
            for (int k = 0; k < 4; ++k) {
                const int t = 4 * c + k;
                if (t >= 1 && t < len) {
                    const float w = __expf(ecur[k]);
                    const int ai = __float_as_int(a);
                    float s0 = 0.f, s1 = 0.f, s2 = 0.f, s3 = 0.f;
                    #pragma unroll
                    for (int qq = 0; qq < 16; ++qq) {
                        s0 = fmaf(__int_as_float(__builtin_amdgcn_readlane(ai, 4 * qq + 0)), Ecol[4 * qq + 0], s0);
                        s1 = fmaf(__int_as_float(__builtin_amdgcn_readlane(ai, 4 * qq + 1)), Ecol[4 * qq + 1], s1);
                        s2 = fmaf(__int_as_float(__builtin_amdgcn_readlane(ai, 4 * qq + 2)), Ecol[4 * qq + 2], s2);
                        s3 = fmaf(__int_as_float(__builtin_amdgcn_readlane(ai, 4 * qq + 3)), Ecol[4 * qq + 3], s3);
                    }
                    a = ((s0 + s1) + (s2 + s3)) * w;
                    if ((t & 7) == 7) {
                        float mm = a;
                        #pragma unroll
                        for (int off = 32; off; off >>= 1) mm = fmaxf(mm, __shfl_xor(mm, off));
                        logscale += __logf(mm);
                        a = a * (1.0f / mm);
                    }
                }
            }
            #pragma unroll
            for (int k = 0; k < 4; ++k) { ecur[k] = enext[k]; enext[k] = efar[k]; }
        }
        float f = a * __expf(Tr[j * LL + TSTOP]);
        float ssum = f;
        #pragma unroll
        for (int off = 32; off; off >>= 1) ssum += __shfl_xor(ssum, off);
        if (j == 0) {
            const float LN2x7 = 7.0f * 0.69314718055994530942f;
            out[b] = logscale + (float)(len - 1) * LN2x7 + __logf(ssum);
        }
    } else {
        const int b = blockIdx.x - BB;
        const int tid = threadIdx.x;
        const int len = lens[b];
        const int* tg = tags + b * SS;
        const float* eb = enc + b * (SS * LL);
        float acc = 0.f;
        for (int t = 1 + tid; t < len; t += 256) {
            int curt = tg[t], prevt = tg[t - 1];
            acc += Tr[prevt * LL + curt] + eb[t * LL + curt];
        }
        #pragma unroll
        for (int off = 32; off; off >>= 1) acc += __shfl_xor(acc, off);
        __shared__ float red[4];
        if ((tid & 63) == 0) red[tid >> 6] = acc;
        __syncthreads();
        if (tid == 0) {
            float tot = (red[0] + red[1]) + (red[2] + red[3]);
            int t0 = tg[0], te = tg[len - 1];
            tot += Tr[TSTART * LL + t0] + eb[t0];
            tot += Tr[te * LL + TSTOP];
            out[BB + b] = tot;
        }
    }
}

extern "C" void kernel_launch(void* const* d_in, const int* in_sizes, int n_in,
                              void* d_out, int out_size, void* d_ws, size_t ws_size,
                              hipStream_t stream) {
    const float* enc  = (const float*)d_in[0];
    const float* Tr   = (const float*)d_in[1];
    const int*   lens = (const int*)d_in[2];
    const int*   tags = (const int*)d_in[3];
    float* out = (float*)d_out;

    const size_t needQ = (size_t)BB * NSEG * 4096 * sizeof(unsigned short);  // 8 MB
    const size_t needS = (size_t)BB * NSEG * 4 * sizeof(float);              // 16 KB
    if (ws_size >= needQ + needS) {
        unsigned short* wsQ = (unsigned short*)d_ws;
        float* wsS = (float*)((char*)d_ws + needQ);
        crf_seg_kernel<<<BB * NSEG * 4 + BB, 64, 0, stream>>>(enc, Tr, lens, tags, wsQ, wsS, out);
        crf_combine_kernel<<<BB, 64, 0, stream>>>(enc, Tr, lens, wsQ, wsS, out);
    } else {
        crf_kernel_fb<<<2 * BB, 256, 0, stream>>>(enc, Tr, lens, tags, out);
    }
}